// Round 5
// baseline (284.869 us; speedup 1.0000x reference)
//
#include <hip/hip_runtime.h>

// LinearAutoDecoder: rgb[n, j] = dot(X[n, 0:63],  W_pos[3*cid[n]+j, :]) +
//                                dot(X[n, 63:127], W_feat[3*cid[n]+j, :])
//
// Strategy: bin points by cluster (hist -> scan -> scatter into d_ws), then a
// compute kernel where each block owns ONE cluster chunk: the 6 weight rows
// live in VGPRs (loaded once per block), so the per-point loop is just
// 4 X-loads + 12 FMA + 15 DPP + store. Half-wave (32 lanes) per point:
// lane l (l32=l&31) covers features {l32, 32+l32, 64+l32, 96+l32} of the
// 127-wide concatenated row; boundary lanes (l32==31) get their special
// weights (Wf[...][0] / zero) folded into the PRELOAD, not the loop.

constexpr int ROWW = 127;   // 63 pos + 64 latent
constexpr int NC   = 256;   // clusters

// ws layout (ints): [0,256) counts/cursors | [256,513) offsets | [576,576+N) idx
constexpr int WS_CUR = 0;
constexpr int WS_OFF = 256;
constexpr int WS_IDX = 576;

template <int CTRL, int RMASK, int BMASK>
__device__ __forceinline__ float dpp_add(float x) {
    int t = __builtin_amdgcn_update_dpp(0, __builtin_bit_cast(int, x),
                                        CTRL, RMASK, BMASK, false);
    return x + __builtin_bit_cast(float, t);
}

// Sum within each 32-lane half; valid in lane 31 (lanes 0-31) and 63 (32-63).
__device__ __forceinline__ float half_sum(float x) {
    x = dpp_add<0xB1,  0xF, 0xF>(x);  // quad_perm xor1
    x = dpp_add<0x4E,  0xF, 0xF>(x);  // quad_perm xor2
    x = dpp_add<0x114, 0xF, 0xE>(x);  // row_shr:4
    x = dpp_add<0x118, 0xF, 0xC>(x);  // row_shr:8  -> lanes 15,31,47,63 = row sums
    x = dpp_add<0x142, 0xA, 0xF>(x);  // row_bcast:15 -> lane31 = rows0+1, lane63 = rows2+3
    return x;
}

// Full 64-lane sum (fallback path); valid in lane 63.
__device__ __forceinline__ float wave_sum63(float x) {
    x = half_sum(x);
    x = dpp_add<0x143, 0xC, 0xF>(x);  // row_bcast:31
    return x;
}

// ---------------- binning pre-pass ----------------

__global__ void k_hist(const int* __restrict__ cid, int* __restrict__ cnt, int npts) {
    int i = blockIdx.x * blockDim.x + threadIdx.x;
    int stride = gridDim.x * blockDim.x;
    for (int n = i; n < npts; n += stride)
        atomicAdd(&cnt[cid[n]], 1);
}

__global__ void k_scan(int* __restrict__ ws, int npts) {
    __shared__ int sh[NC];
    const int t = threadIdx.x;
    const int c = ws[WS_CUR + t];
    sh[t] = c;
    __syncthreads();
    #pragma unroll
    for (int off = 1; off < NC; off <<= 1) {
        int v = (t >= off) ? sh[t - off] : 0;
        __syncthreads();
        sh[t] += v;
        __syncthreads();
    }
    const int excl = sh[t] - c;
    ws[WS_OFF + t] = excl;        // exclusive offsets
    if (t == NC - 1) ws[WS_OFF + NC] = sh[t];   // total == npts
    ws[WS_CUR + t] = excl;        // cursors for scatter
}

__global__ void k_scatter(const int* __restrict__ cid, int* __restrict__ ws, int npts) {
    int i = blockIdx.x * blockDim.x + threadIdx.x;
    int stride = gridDim.x * blockDim.x;
    for (int n = i; n < npts; n += stride) {
        int pos = atomicAdd(&ws[WS_CUR + cid[n]], 1);
        ws[WS_IDX + pos] = n;
    }
}

// ---------------- main compute ----------------

__global__ __launch_bounds__(256, 8) void k_main(
    const float* __restrict__ X,
    const float* __restrict__ Wp,   // [768][63]
    const float* __restrict__ Wf,   // [768][64]
    const int*   __restrict__ ws,   // offsets at WS_OFF, idx at WS_IDX
    float*       __restrict__ out)  // [N][3]
{
    const int cl    = blockIdx.x >> 3;        // 8 blocks per cluster
    const int chunk = blockIdx.x & 7;
    const int lane  = threadIdx.x & 63;
    const int wv    = threadIdx.x >> 6;
    const int s     = chunk * 4 + wv;         // sub-wave id within cluster, 0..31
    const int l32   = lane & 31;
    const int half  = lane >> 5;
    const bool edge = (l32 == 31);

    // ---- preload weights into VGPRs (boundary specials folded in) ----
    // lane covers features f_k = 32k + l32:
    //  k=0: Wp[r][l32]
    //  k=1: l32<31 -> Wp[r][32+l32] ; l32==31 -> f=63 -> Wf[r][0]
    //  k=2: Wf[r][1+l32]
    //  k=3: l32<31 -> Wf[r][33+l32] ; l32==31 -> f=127 (dead) -> 0
    float w[3][4];
    #pragma unroll
    for (int j = 0; j < 3; ++j) {
        const size_t r = (size_t)(3 * cl + j);
        const float* wp = Wp + r * 63;
        const float* wf = Wf + r * 64;
        w[j][0] = wp[l32];
        w[j][1] = edge ? wf[0] : wp[32 + l32];
        w[j][2] = wf[1 + l32];
        w[j][3] = edge ? 0.0f : wf[33 + l32];
    }

    const int beg = ws[WS_OFF + cl];
    const int end = ws[WS_OFF + cl + 1];
    const int o0 = l32, o1 = 32 + l32, o2 = 64 + l32;
    const int o3 = edge ? 126 : 96 + l32;     // clamp dead feature 127 in-bounds

    const int* idxb = ws + WS_IDX;

    for (int q0 = beg + s; q0 < end; q0 += 64) {
        const int q1 = q0 + 32;
        const bool h1 = q1 < end;

        int p0 = idxb[q0];
        int p1 = h1 ? idxb[q1] : p0;
        p0 = __builtin_amdgcn_readfirstlane(p0);
        p1 = __builtin_amdgcn_readfirstlane(p1);

        const int  pl = half ? p1 : p0;
        const float* xr = X + (size_t)pl * ROWW;
        const float x0 = xr[o0];
        const float x1 = xr[o1];
        const float x2 = xr[o2];
        const float x3 = xr[o3];

        float a0 = fmaf(x1, w[0][1], x0 * w[0][0]) + fmaf(x3, w[0][3], x2 * w[0][2]);
        float a1 = fmaf(x1, w[1][1], x0 * w[1][0]) + fmaf(x3, w[1][3], x2 * w[1][2]);
        float a2 = fmaf(x1, w[2][1], x0 * w[2][0]) + fmaf(x3, w[2][3], x2 * w[2][2]);

        a0 = half_sum(a0);
        a1 = half_sum(a1);
        a2 = half_sum(a2);

        // lane 31 holds point p0's sums; lane 63 holds p1's.
        if (edge && (half ? h1 : true)) {
            float* o = out + 3 * (size_t)pl;
            o[0] = a0; o[1] = a1; o[2] = a2;
        }
    }
}

// ---------------- fallback (no-ws path, round-3 kernel) ----------------

__global__ __launch_bounds__(256, 8) void lad_fallback(
    const float* __restrict__ X, const int* __restrict__ cid,
    const float* __restrict__ Wp, const float* __restrict__ Wf,
    float* __restrict__ out, int npts)
{
    const int lane  = threadIdx.x & 63;
    const int wid   = (blockIdx.x * blockDim.x + threadIdx.x) >> 6;
    const int nW    = (gridDim.x * blockDim.x) >> 6;
    const int lanec = (lane < 63) ? lane : 62;
    const bool l63  = (lane == 63);

    for (int n = wid; n < npts; n += 2 * nW) {
        const int n2 = n + nW;
        const bool has2 = (n2 < npts);

        const float* x0 = X + (size_t)n * ROWW;
        float xa0 = x0[lane];
        float xb0 = x0[63 + lane];
        int   c0  = __builtin_amdgcn_readfirstlane(cid[n]);

        float xa1 = 0.0f, xb1 = 0.0f;
        int   c1  = 0;
        if (has2) {
            const float* x1 = X + (size_t)n2 * ROWW;
            xa1 = x1[lane];
            xb1 = x1[63 + lane];
            c1  = __builtin_amdgcn_readfirstlane(cid[n2]);
        }
        if (l63) { xa0 = 0.0f; xa1 = 0.0f; }

        const float* wp0 = Wp + (size_t)(3 * c0) * 63;
        const float* wf0 = Wf + (size_t)(3 * c0) * 64;
        const float* wp1 = Wp + (size_t)(3 * c1) * 63;
        const float* wf1 = Wf + (size_t)(3 * c1) * 64;

        float a00 = fmaf(xa0, wp0[lanec],       xb0 * wf0[lane]);
        float a01 = fmaf(xa0, wp0[63 + lanec],  xb0 * wf0[64 + lane]);
        float a02 = fmaf(xa0, wp0[126 + lanec], xb0 * wf0[128 + lane]);
        float a10 = fmaf(xa1, wp1[lanec],       xb1 * wf1[lane]);
        float a11 = fmaf(xa1, wp1[63 + lanec],  xb1 * wf1[64 + lane]);
        float a12 = fmaf(xa1, wp1[126 + lanec], xb1 * wf1[128 + lane]);

        a00 = wave_sum63(a00); a01 = wave_sum63(a01); a02 = wave_sum63(a02);
        a10 = wave_sum63(a10); a11 = wave_sum63(a11); a12 = wave_sum63(a12);

        if (l63) {
            float* o0 = out + 3 * (size_t)n;
            o0[0] = a00; o0[1] = a01; o0[2] = a02;
            if (has2) {
                float* o1 = out + 3 * (size_t)n2;
                o1[0] = a10; o1[1] = a11; o1[2] = a12;
            }
        }
    }
}

extern "C" void kernel_launch(void* const* d_in, const int* in_sizes, int n_in,
                              void* d_out, int out_size, void* d_ws, size_t ws_size,
                              hipStream_t stream) {
    const float* X   = (const float*)d_in[0];
    const int*   cid = (const int*)d_in[1];
    const float* Wp  = (const float*)d_in[2];
    const float* Wf  = (const float*)d_in[3];
    float* out = (float*)d_out;
    const int npts = in_sizes[1];   // cluster_ids element count == N

    const size_t ws_needed = (size_t)(WS_IDX + npts) * sizeof(int);
    if (ws_size < ws_needed) {
        dim3 grid(2048), block(256);
        hipLaunchKernelGGL(lad_fallback, grid, block, 0, stream,
                           X, cid, Wp, Wf, out, npts);
        return;
    }

    int* ws = (int*)d_ws;
    hipMemsetAsync(ws, 0, NC * sizeof(int), stream);
    hipLaunchKernelGGL(k_hist,    dim3(256),  dim3(256), 0, stream, cid, ws + WS_CUR, npts);
    hipLaunchKernelGGL(k_scan,    dim3(1),    dim3(NC),  0, stream, ws, npts);
    hipLaunchKernelGGL(k_scatter, dim3(256),  dim3(256), 0, stream, cid, ws, npts);
    hipLaunchKernelGGL(k_main,    dim3(8 * NC), dim3(256), 0, stream, X, Wp, Wf, ws, out);
}

// Round 6
// 60.346 us; speedup vs baseline: 4.7206x; 4.7206x over previous
//
#include <hip/hip_runtime.h>

// LinearAutoDecoder: rgb[n, j] = dot(X[n, 0:63],  W_pos[3*cid[n]+j, :]) +
//                                dot(X[n, 63:127], W_feat[3*cid[n]+j, :])
//
// Counting-sort points by cluster (LDS-hist everywhere -> cheap), then a
// compute kernel where each block owns ONE cluster: its 6 weight rows live in
// VGPRs (loaded once), so the per-point loop is 4 X-loads + ~15 VALU + 15 DPP
// shared by 2 points (half-wave per point), software-pipelined 2-deep on the
// idx -> X chain. No per-point weight loads, no cid->weight dependent chain.

constexpr int ROWW = 127;   // 63 pos + 64 latent
constexpr int NC   = 256;   // clusters

// ws layout (ints): [0,256) counts/cursors | [256,513) offsets | [576,576+N) idx
constexpr int WS_CUR = 0;
constexpr int WS_OFF = 256;
constexpr int WS_IDX = 576;

template <int CTRL, int RMASK, int BMASK>
__device__ __forceinline__ float dpp_add(float x) {
    int t = __builtin_amdgcn_update_dpp(0, __builtin_bit_cast(int, x),
                                        CTRL, RMASK, BMASK, false);
    return x + __builtin_bit_cast(float, t);
}

// Sum within each 32-lane half; valid in lane 31 (lanes 0-31) and 63 (32-63).
__device__ __forceinline__ float half_sum(float x) {
    x = dpp_add<0xB1,  0xF, 0xF>(x);  // quad_perm xor1
    x = dpp_add<0x4E,  0xF, 0xF>(x);  // quad_perm xor2
    x = dpp_add<0x114, 0xF, 0xE>(x);  // row_shr:4
    x = dpp_add<0x118, 0xF, 0xC>(x);  // row_shr:8
    x = dpp_add<0x142, 0xA, 0xF>(x);  // row_bcast:15
    return x;
}

// ---------------- binning pre-pass (LDS histograms) ----------------

__global__ __launch_bounds__(NC) void k_hist(const int* __restrict__ cid,
                                             int* __restrict__ cnt, int npts) {
    __shared__ int lh[NC];
    const int t = threadIdx.x;
    lh[t] = 0;
    __syncthreads();
    for (int n = blockIdx.x * blockDim.x + t; n < npts; n += gridDim.x * blockDim.x)
        atomicAdd(&lh[cid[n]], 1);
    __syncthreads();
    const int c = lh[t];
    if (c) atomicAdd(&cnt[t], c);
}

__global__ __launch_bounds__(NC) void k_scan(int* __restrict__ ws, int npts) {
    __shared__ int sh[NC];
    const int t = threadIdx.x;
    const int c = ws[WS_CUR + t];
    sh[t] = c;
    __syncthreads();
    #pragma unroll
    for (int off = 1; off < NC; off <<= 1) {
        int v = (t >= off) ? sh[t - off] : 0;
        __syncthreads();
        sh[t] += v;
        __syncthreads();
    }
    const int excl = sh[t] - c;
    ws[WS_OFF + t] = excl;                      // exclusive offsets
    if (t == NC - 1) ws[WS_OFF + NC] = sh[t];   // total == npts
    ws[WS_CUR + t] = excl;                      // cursors for scatter
}

__global__ __launch_bounds__(NC) void k_scatter(const int* __restrict__ cid,
                                                int* __restrict__ ws, int npts) {
    __shared__ int lh[NC];    // local hist, then local cursors
    __shared__ int base[NC];  // global base of this block's run per cluster
    const int t = threadIdx.x;
    const int per = (npts + gridDim.x - 1) / gridDim.x;
    const int beg = blockIdx.x * per;
    const int end = min(beg + per, npts);

    lh[t] = 0;
    __syncthreads();
    for (int n = beg + t; n < end; n += blockDim.x)
        atomicAdd(&lh[cid[n]], 1);
    __syncthreads();
    const int c = lh[t];
    base[t] = c ? atomicAdd(&ws[WS_CUR + t], c) : 0;
    lh[t] = 0;
    __syncthreads();
    int* idx = ws + WS_IDX;
    for (int n = beg + t; n < end; n += blockDim.x) {
        const int cc  = cid[n];
        const int pos = base[cc] + atomicAdd(&lh[cc], 1);
        idx[pos] = n;
    }
}

// ---------------- main compute ----------------

__global__ __launch_bounds__(256, 8) void k_main(
    const float* __restrict__ X,
    const float* __restrict__ Wp,   // [768][63]
    const float* __restrict__ Wf,   // [768][64]
    const int*   __restrict__ ws,   // offsets at WS_OFF, idx at WS_IDX
    float*       __restrict__ out)  // [N][3]
{
    const int cl    = blockIdx.x >> 3;        // 8 blocks per cluster
    const int chunk = blockIdx.x & 7;
    const int lane  = threadIdx.x & 63;
    const int wv    = threadIdx.x >> 6;
    const int s     = chunk * 4 + wv;         // sub-wave id within cluster, 0..31
    const int l32   = lane & 31;
    const int half  = lane >> 5;
    const bool edge = (l32 == 31);

    // ---- preload weights into VGPRs (boundary specials folded in) ----
    // lane covers features f_k = 32k + l32:
    //  k=0: Wp[r][l32]
    //  k=1: l32<31 -> Wp[r][32+l32] ; l32==31 -> f=63 -> Wf[r][0]
    //  k=2: Wf[r][1+l32]
    //  k=3: l32<31 -> Wf[r][33+l32] ; l32==31 -> f=127 (dead) -> 0
    float w[3][4];
    #pragma unroll
    for (int j = 0; j < 3; ++j) {
        const size_t r = (size_t)(3 * cl + j);
        const float* wp = Wp + r * 63;
        const float* wf = Wf + r * 64;
        w[j][0] = wp[l32];
        w[j][1] = edge ? wf[0] : wp[32 + l32];
        w[j][2] = wf[1 + l32];
        w[j][3] = edge ? 0.0f : wf[33 + l32];
    }

    const int beg = ws[WS_OFF + cl];
    const int end = ws[WS_OFF + cl + 1];
    const int o0 = l32, o1 = 32 + l32, o2 = 64 + l32;
    const int o3 = edge ? 126 : 96 + l32;     // clamp dead feature 127 in-bounds
    const int* idxb = ws + WS_IDX;

    int q = beg + s;
    if (q >= end) return;                     // wave-uniform exit

    // ---- prologue: fetch pair 0's indices + X rows ----
    int pa, pb; bool hb;
    float x0, x1, x2, x3;
    {
        pa = __builtin_amdgcn_readfirstlane(idxb[q]);
        const int qb = q + 32;
        hb = qb < end;
        pb = hb ? __builtin_amdgcn_readfirstlane(idxb[qb]) : pa;
        const float* xr = X + (size_t)(half ? pb : pa) * ROWW;
        x0 = xr[o0]; x1 = xr[o1]; x2 = xr[o2]; x3 = xr[o3];
    }

    while (true) {
        // ---- prefetch next pair (idx -> X) to overlap current compute ----
        const int qn = q + 64;
        const bool more = qn < end;
        int pa_n = pa, pb_n = pb; bool hb_n = false;
        float y0 = 0.f, y1 = 0.f, y2 = 0.f, y3 = 0.f;
        if (more) {
            pa_n = __builtin_amdgcn_readfirstlane(idxb[qn]);
            const int qbn = qn + 32;
            hb_n = qbn < end;
            pb_n = hb_n ? __builtin_amdgcn_readfirstlane(idxb[qbn]) : pa_n;
            const float* yr = X + (size_t)(half ? pb_n : pa_n) * ROWW;
            y0 = yr[o0]; y1 = yr[o1]; y2 = yr[o2]; y3 = yr[o3];
        }

        // ---- compute current pair ----
        float a0 = fmaf(x1, w[0][1], x0 * w[0][0]) + fmaf(x3, w[0][3], x2 * w[0][2]);
        float a1 = fmaf(x1, w[1][1], x0 * w[1][0]) + fmaf(x3, w[1][3], x2 * w[1][2]);
        float a2 = fmaf(x1, w[2][1], x0 * w[2][0]) + fmaf(x3, w[2][3], x2 * w[2][2]);
        a0 = half_sum(a0);
        a1 = half_sum(a1);
        a2 = half_sum(a2);

        // lane 31 holds point pa's sums; lane 63 holds pb's.
        if (edge && (!half || hb)) {
            float* o = out + 3 * (size_t)(half ? pb : pa);
            o[0] = a0; o[1] = a1; o[2] = a2;
        }

        if (!more) break;
        q = qn; pa = pa_n; pb = pb_n; hb = hb_n;
        x0 = y0; x1 = y1; x2 = y2; x3 = y3;
    }
}

// ---------------- fallback (ws too small): round-3 direct kernel ----------------

__device__ __forceinline__ float wave_sum63(float x) {
    x = half_sum(x);
    x = dpp_add<0x143, 0xC, 0xF>(x);  // row_bcast:31
    return x;
}

__global__ __launch_bounds__(256, 8) void lad_fallback(
    const float* __restrict__ X, const int* __restrict__ cid,
    const float* __restrict__ Wp, const float* __restrict__ Wf,
    float* __restrict__ out, int npts)
{
    const int lane  = threadIdx.x & 63;
    const int wid   = (blockIdx.x * blockDim.x + threadIdx.x) >> 6;
    const int nW    = (gridDim.x * blockDim.x) >> 6;
    const int lanec = (lane < 63) ? lane : 62;
    const bool l63  = (lane == 63);

    for (int n = wid; n < npts; n += 2 * nW) {
        const int n2 = n + nW;
        const bool has2 = (n2 < npts);

        const float* x0 = X + (size_t)n * ROWW;
        float xa0 = x0[lane];
        float xb0 = x0[63 + lane];
        int   c0  = __builtin_amdgcn_readfirstlane(cid[n]);

        float xa1 = 0.0f, xb1 = 0.0f;
        int   c1  = 0;
        if (has2) {
            const float* x1 = X + (size_t)n2 * ROWW;
            xa1 = x1[lane];
            xb1 = x1[63 + lane];
            c1  = __builtin_amdgcn_readfirstlane(cid[n2]);
        }
        if (l63) { xa0 = 0.0f; xa1 = 0.0f; }

        const float* wp0 = Wp + (size_t)(3 * c0) * 63;
        const float* wf0 = Wf + (size_t)(3 * c0) * 64;
        const float* wp1 = Wp + (size_t)(3 * c1) * 63;
        const float* wf1 = Wf + (size_t)(3 * c1) * 64;

        float a00 = fmaf(xa0, wp0[lanec],       xb0 * wf0[lane]);
        float a01 = fmaf(xa0, wp0[63 + lanec],  xb0 * wf0[64 + lane]);
        float a02 = fmaf(xa0, wp0[126 + lanec], xb0 * wf0[128 + lane]);
        float a10 = fmaf(xa1, wp1[lanec],       xb1 * wf1[lane]);
        float a11 = fmaf(xa1, wp1[63 + lanec],  xb1 * wf1[64 + lane]);
        float a12 = fmaf(xa1, wp1[126 + lanec], xb1 * wf1[128 + lane]);

        a00 = wave_sum63(a00); a01 = wave_sum63(a01); a02 = wave_sum63(a02);
        a10 = wave_sum63(a10); a11 = wave_sum63(a11); a12 = wave_sum63(a12);

        if (l63) {
            float* o0 = out + 3 * (size_t)n;
            o0[0] = a00; o0[1] = a01; o0[2] = a02;
            if (has2) {
                float* o1 = out + 3 * (size_t)n2;
                o1[0] = a10; o1[1] = a11; o1[2] = a12;
            }
        }
    }
}

extern "C" void kernel_launch(void* const* d_in, const int* in_sizes, int n_in,
                              void* d_out, int out_size, void* d_ws, size_t ws_size,
                              hipStream_t stream) {
    const float* X   = (const float*)d_in[0];
    const int*   cid = (const int*)d_in[1];
    const float* Wp  = (const float*)d_in[2];
    const float* Wf  = (const float*)d_in[3];
    float* out = (float*)d_out;
    const int npts = in_sizes[1];   // cluster_ids element count == N

    const size_t ws_needed = (size_t)(WS_IDX + npts) * sizeof(int);
    if (ws_size < ws_needed) {
        dim3 grid(2048), block(256);
        hipLaunchKernelGGL(lad_fallback, grid, block, 0, stream,
                           X, cid, Wp, Wf, out, npts);
        return;
    }

    int* ws = (int*)d_ws;
    hipMemsetAsync(ws, 0, NC * sizeof(int), stream);
    hipLaunchKernelGGL(k_hist,    dim3(NC),     dim3(NC),  0, stream, cid, ws + WS_CUR, npts);
    hipLaunchKernelGGL(k_scan,    dim3(1),      dim3(NC),  0, stream, ws, npts);
    hipLaunchKernelGGL(k_scatter, dim3(NC),     dim3(NC),  0, stream, cid, ws, npts);
    hipLaunchKernelGGL(k_main,    dim3(8 * NC), dim3(256), 0, stream, X, Wp, Wf, ws, out);
}

// Round 7
// 49.611 us; speedup vs baseline: 5.7421x; 1.2164x over previous
//
#include <hip/hip_runtime.h>

// LinearAutoDecoder: rgb[n, j] = dot(X[n, 0:63],  W_pos[3*cid[n]+j, :]) +
//                                dot(X[n, 63:127], W_feat[3*cid[n]+j, :])
//
// Direct single pass in natural point order (X coalesced, no binning).
// Half-wave (32 lanes) per point: lane l32 covers features {l32, 32+l32,
// 64+l32, 96+l32}; the lane-31 boundary specials (feature 63 -> Wf[r][0],
// feature 127 -> 0) are folded into a pre-packed weight table built once per
// launch in d_ws:  Wq[c][l32][16] = 12 weights (j=0..2 x k=0..3) + pad.
// Per point the weights are 3 float4 loads (64B-aligned), address is pure
// VGPR math from cid (no readfirstlane chain). cid+X for the next pair are
// prefetched 1 iteration ahead. Reduction = 5-level DPP per 32-lane half.

constexpr int ROWW = 127;   // 63 pos + 64 latent
constexpr int NC   = 256;   // clusters

template <int CTRL, int RMASK, int BMASK>
__device__ __forceinline__ float dpp_add(float x) {
    int t = __builtin_amdgcn_update_dpp(0, __builtin_bit_cast(int, x),
                                        CTRL, RMASK, BMASK, false);
    return x + __builtin_bit_cast(float, t);
}

// Sum within each 32-lane half; valid in lane 31 (lanes 0-31) and 63 (32-63).
__device__ __forceinline__ float half_sum(float x) {
    x = dpp_add<0xB1,  0xF, 0xF>(x);  // quad_perm xor1
    x = dpp_add<0x4E,  0xF, 0xF>(x);  // quad_perm xor2
    x = dpp_add<0x114, 0xF, 0xE>(x);  // row_shr:4
    x = dpp_add<0x118, 0xF, 0xC>(x);  // row_shr:8
    x = dpp_add<0x142, 0xA, 0xF>(x);  // row_bcast:15
    return x;
}

__device__ __forceinline__ float wave_sum63(float x) {
    x = half_sum(x);
    x = dpp_add<0x143, 0xC, 0xF>(x);  // row_bcast:31
    return x;
}

// ---------------- weight pack: Wq[c][l32][16] ----------------
// k=0: Wp[r][l32]
// k=1: l32<31 -> Wp[r][32+l32] ; l32==31 -> Wf[r][0]   (feature 63)
// k=2: Wf[r][1+l32]
// k=3: l32<31 -> Wf[r][33+l32] ; l32==31 -> 0          (feature 127, dead)
__global__ __launch_bounds__(256) void k_pack(const float* __restrict__ Wp,
                                              const float* __restrict__ Wf,
                                              float* __restrict__ Wq) {
    const int t    = threadIdx.x;
    const int c    = blockIdx.x * 8 + (t >> 5);
    const int l32  = t & 31;
    const bool edge = (l32 == 31);
    float* dst = Wq + ((size_t)(c * 32 + l32) << 4);
    #pragma unroll
    for (int j = 0; j < 3; ++j) {
        const size_t r = (size_t)(3 * c + j);
        const float* wp = Wp + r * 63;
        const float* wf = Wf + r * 64;
        dst[j * 4 + 0] = wp[l32];
        dst[j * 4 + 1] = edge ? wf[0] : wp[32 + l32];
        dst[j * 4 + 2] = wf[1 + l32];
        dst[j * 4 + 3] = edge ? 0.0f : wf[33 + l32];
    }
}

// ---------------- main compute ----------------

__global__ __launch_bounds__(256, 8) void k_main(
    const float* __restrict__ X,
    const int*   __restrict__ cid,
    const float* __restrict__ Wq,   // [256][32][16]
    float*       __restrict__ out,  // [N][3]
    int npts)
{
    const int lane = threadIdx.x & 63;
    const int l32  = lane & 31;
    const int half = lane >> 5;
    const bool edge = (l32 == 31);
    const int wid  = (blockIdx.x * blockDim.x + threadIdx.x) >> 6;
    const int nW   = (gridDim.x * blockDim.x) >> 6;
    const int o3   = edge ? 126 : 96 + l32;   // clamp dead feature 127 in-bounds
    const int npairs = (npts + 1) >> 1;

    int g = wid;
    if (g >= npairs) return;                  // wave-uniform

    // ---- prologue: pair g's cid + X ----
    int p = 2 * g + half;
    if (p >= npts) p = npts - 1;              // odd-npts clamp (dup write benign)
    int c = cid[p];
    {
        const float* xr = X + (size_t)p * ROWW;
        // loads issued below inside loop body via x regs
    }
    const float* xr0 = X + (size_t)p * ROWW;
    float x0 = xr0[l32], x1 = xr0[32 + l32], x2 = xr0[64 + l32], x3 = xr0[o3];

    while (true) {
        // ---- prefetch next pair's cid + X (overlaps current compute) ----
        const int g_n = g + nW;
        const bool more = g_n < npairs;
        int p_n = p, c_n = c;
        float y0 = 0.f, y1 = 0.f, y2 = 0.f, y3 = 0.f;
        if (more) {
            p_n = 2 * g_n + half;
            if (p_n >= npts) p_n = npts - 1;
            c_n = cid[p_n];
            const float* yr = X + (size_t)p_n * ROWW;
            y0 = yr[l32]; y1 = yr[32 + l32]; y2 = yr[64 + l32]; y3 = yr[o3];
        }

        // ---- current pair: 3 float4 weight loads + 12 FMA + 15 DPP ----
        const float4* wrow = (const float4*)(Wq + ((size_t)((c << 5) + l32) << 4));
        const float4 w0 = wrow[0];
        const float4 w1 = wrow[1];
        const float4 w2 = wrow[2];

        float a0 = fmaf(x0, w0.x, fmaf(x1, w0.y, fmaf(x2, w0.z, x3 * w0.w)));
        float a1 = fmaf(x0, w1.x, fmaf(x1, w1.y, fmaf(x2, w1.z, x3 * w1.w)));
        float a2 = fmaf(x0, w2.x, fmaf(x1, w2.y, fmaf(x2, w2.z, x3 * w2.w)));

        a0 = half_sum(a0);
        a1 = half_sum(a1);
        a2 = half_sum(a2);

        // lane 31 holds its half's point sums; lane 63 the other's.
        if (edge) {
            float* o = out + 3 * (size_t)p;
            o[0] = a0; o[1] = a1; o[2] = a2;
        }

        if (!more) break;
        g = g_n; p = p_n; c = c_n;
        x0 = y0; x1 = y1; x2 = y2; x3 = y3;
    }
}

// ---------------- fallback (ws too small): round-3 direct kernel ----------------

__global__ __launch_bounds__(256, 8) void lad_fallback(
    const float* __restrict__ X, const int* __restrict__ cid,
    const float* __restrict__ Wp, const float* __restrict__ Wf,
    float* __restrict__ out, int npts)
{
    const int lane  = threadIdx.x & 63;
    const int wid   = (blockIdx.x * blockDim.x + threadIdx.x) >> 6;
    const int nW    = (gridDim.x * blockDim.x) >> 6;
    const int lanec = (lane < 63) ? lane : 62;
    const bool l63  = (lane == 63);

    for (int n = wid; n < npts; n += 2 * nW) {
        const int n2 = n + nW;
        const bool has2 = (n2 < npts);

        const float* x0 = X + (size_t)n * ROWW;
        float xa0 = x0[lane];
        float xb0 = x0[63 + lane];
        int   c0  = __builtin_amdgcn_readfirstlane(cid[n]);

        float xa1 = 0.0f, xb1 = 0.0f;
        int   c1  = 0;
        if (has2) {
            const float* x1 = X + (size_t)n2 * ROWW;
            xa1 = x1[lane];
            xb1 = x1[63 + lane];
            c1  = __builtin_amdgcn_readfirstlane(cid[n2]);
        }
        if (l63) { xa0 = 0.0f; xa1 = 0.0f; }

        const float* wp0 = Wp + (size_t)(3 * c0) * 63;
        const float* wf0 = Wf + (size_t)(3 * c0) * 64;
        const float* wp1 = Wp + (size_t)(3 * c1) * 63;
        const float* wf1 = Wf + (size_t)(3 * c1) * 64;

        float a00 = fmaf(xa0, wp0[lanec],       xb0 * wf0[lane]);
        float a01 = fmaf(xa0, wp0[63 + lanec],  xb0 * wf0[64 + lane]);
        float a02 = fmaf(xa0, wp0[126 + lanec], xb0 * wf0[128 + lane]);
        float a10 = fmaf(xa1, wp1[lanec],       xb1 * wf1[lane]);
        float a11 = fmaf(xa1, wp1[63 + lanec],  xb1 * wf1[64 + lane]);
        float a12 = fmaf(xa1, wp1[126 + lanec], xb1 * wf1[128 + lane]);

        a00 = wave_sum63(a00); a01 = wave_sum63(a01); a02 = wave_sum63(a02);
        a10 = wave_sum63(a10); a11 = wave_sum63(a11); a12 = wave_sum63(a12);

        if (l63) {
            float* o0 = out + 3 * (size_t)n;
            o0[0] = a00; o0[1] = a01; o0[2] = a02;
            if (has2) {
                float* o1 = out + 3 * (size_t)n2;
                o1[0] = a10; o1[1] = a11; o1[2] = a12;
            }
        }
    }
}

extern "C" void kernel_launch(void* const* d_in, const int* in_sizes, int n_in,
                              void* d_out, int out_size, void* d_ws, size_t ws_size,
                              hipStream_t stream) {
    const float* X   = (const float*)d_in[0];
    const int*   cid = (const int*)d_in[1];
    const float* Wp  = (const float*)d_in[2];
    const float* Wf  = (const float*)d_in[3];
    float* out = (float*)d_out;
    const int npts = in_sizes[1];   // cluster_ids element count == N

    const size_t wq_bytes = (size_t)NC * 32 * 16 * sizeof(float);  // 512 KiB
    if (ws_size < wq_bytes) {
        dim3 grid(2048), block(256);
        hipLaunchKernelGGL(lad_fallback, grid, block, 0, stream,
                           X, cid, Wp, Wf, out, npts);
        return;
    }

    float* Wq = (float*)d_ws;
    hipLaunchKernelGGL(k_pack, dim3(NC / 8), dim3(256), 0, stream, Wp, Wf, Wq);
    hipLaunchKernelGGL(k_main, dim3(2048),   dim3(256), 0, stream,
                       X, cid, Wq, out, npts);
}